// Round 5
// baseline (554.471 us; speedup 1.0000x reference)
//
#include <hip/hip_runtime.h>
#include <stdint.h>

// Inputs: float32. Output: float32 (reference's output dtype).
#define B_   8
#define L_   1024
#define D_   64
#define H_   8
#define HD_  512
#define NREL 301
#define RP   320   // padded rel dim for Ws/rvT (10 K32 MFMA frags)
#define QRP  304   // QR row stride (19 * 16)
#define RKB  304   // rkB rows (301 + 3 dup of row 300)

typedef short bf16x8 __attribute__((ext_vector_type(8)));
typedef float f32x4  __attribute__((ext_vector_type(4)));

#define MFMA16(a,b,c) __builtin_amdgcn_mfma_f32_16x16x32_bf16((a),(b),(c),0,0,0)

__device__ __forceinline__ float bf2f(short s){
  union { unsigned u; float f; } v; v.u = ((unsigned)(unsigned short)s) << 16; return v.f;
}
__device__ __forceinline__ short f2bf(float f){
  union { float f; unsigned u; } v; v.f = f;
  v.u += ((v.u >> 16) & 1u) + 0x7fffu;   // RNE
  return (short)(v.u >> 16);
}
__device__ __forceinline__ bf16x8 cvt8(const float* p){
  float4 x0 = *(const float4*)p, x1 = *(const float4*)(p + 4);
  bf16x8 r;
  r[0]=f2bf(x0.x); r[1]=f2bf(x0.y); r[2]=f2bf(x0.z); r[3]=f2bf(x0.w);
  r[4]=f2bf(x1.x); r[5]=f2bf(x1.y); r[6]=f2bf(x1.z); r[7]=f2bf(x1.w);
  return r;
}

// ---------------- Kernel 0: weight transpose + f32->bf16 into workspace -----
#define PREP_TOTAL (4*32768 + 64*RP + RKB*64)   // 171008
__global__ __launch_bounds__(256)
void prep_kernel(const float* __restrict__ Wq, const float* __restrict__ Wk,
                 const float* __restrict__ Wv, const float* __restrict__ Wo,
                 const float* __restrict__ rk, const float* __restrict__ rv,
                 short* __restrict__ ws16){
  int idx = blockIdx.x*256 + threadIdx.x;
  short* WqT = ws16;                 // [512][64]
  short* WkT = ws16 + 32768;
  short* WvT = ws16 + 65536;
  short* WoT = ws16 + 98304;         // [64][512]
  short* rvT = ws16 + 131072;        // [64][RP], cols>=301 zero
  short* rkB = ws16 + 131072 + 64*RP;// [RKB][64], rows>=301 dup row 300
  if (idx < 32768){ WqT[idx] = f2bf(Wq[(idx&63)*HD_ + (idx>>6)]); return; }
  idx -= 32768;
  if (idx < 32768){ WkT[idx] = f2bf(Wk[(idx&63)*HD_ + (idx>>6)]); return; }
  idx -= 32768;
  if (idx < 32768){ WvT[idx] = f2bf(Wv[(idx&63)*HD_ + (idx>>6)]); return; }
  idx -= 32768;
  if (idx < 32768){ WoT[idx] = f2bf(Wo[(idx&511)*D_ + (idx>>9)]); return; }
  idx -= 32768;
  if (idx < 64*RP){ int c = idx/RP, r = idx - c*RP;
                    rvT[idx] = (r < NREL) ? f2bf(rv[r*D_ + c]) : (short)0; return; }
  idx -= 64*RP;
  if (idx < RKB*64){ int tr = idx>>6, d = idx&63;
                     int src = (tr > 300) ? 300 : tr;
                     rkB[idx] = f2bf(rk[src*D_ + d]); }
}

// ---------------- Kernel 1: fused QKV projection — direct loads, no LDS ----
__global__ __launch_bounds__(256)
void proj_kernel(const float* __restrict__ qin, const float* __restrict__ kin,
                 const float* __restrict__ vin,
                 const short* __restrict__ WqT, const short* __restrict__ WkT,
                 const short* __restrict__ WvT,
                 short* __restrict__ Qo, short* __restrict__ Ko, short* __restrict__ VTo){
  int t = threadIdx.x, w = t>>6, l = t&63;
  int mt = blockIdx.x, ny = blockIdx.y, mat = blockIdx.z;
  const float* in = (mat==0) ? qin : (mat==1 ? kin : vin);
  const short* WT = (mat==0) ? WqT : (mat==1 ? WkT : WvT);
  int arow = mt*64 + w*16 + (l&15);
  bf16x8 a[2];
#pragma unroll
  for (int kf=0;kf<2;++kf)
    a[kf] = cvt8(in + arow*D_ + (l>>4)*8 + kf*32);
  f32x4 acc[4];
#pragma unroll
  for (int nt=0;nt<4;++nt){
    f32x4 z = {0.f,0.f,0.f,0.f}; acc[nt] = z;
#pragma unroll
    for (int kf=0;kf<2;++kf){
      bf16x8 bfr = *(const bf16x8*)(WT + (ny*64 + nt*16 + (l&15))*D_ + (l>>4)*8 + kf*32);
      acc[nt] = MFMA16(a[kf], bfr, acc[nt]);
    }
  }
  float scale = (mat==0) ? 0.125f : 1.0f;   // fold 1/sqrt(64) into Q
#pragma unroll
  for (int nt=0;nt<4;++nt){
    int hd = ny*64 + nt*16 + (l&15);
    int h = hd >> 6, d = hd & 63;
#pragma unroll
    for (int j=0;j<4;++j){
      int m = mt*64 + w*16 + (l>>4)*4 + j;
      int b = m >> 10, lr = m & 1023;
      short vv = f2bf(acc[nt][j] * scale);
      if (mat==2) VTo[(((b*H_ + h)*D_ + d)<<10) + lr] = vv;          // [B,H,D,L]
      else {
        short* O = (mat==0) ? Qo : Ko;                               // [B,H,L,D]
        O[((((b*H_ + h)<<10) + lr)*D_) + d] = vv;
      }
    }
  }
}

// ---------------- Kernel 2: fused relative attention — direct loads --------
// LDS only for QRs (gather), Ws (scatter), Pt (P transpose). All wave-private,
// all linear, no __syncthreads.
__global__ __launch_bounds__(256)
void attn_kernel(const short* __restrict__ Q, const short* __restrict__ K,
                 const short* __restrict__ VT, const short* __restrict__ rkB,
                 const short* __restrict__ rvT, short* __restrict__ X){
  __shared__ short QRs[64*QRP];     // 38912 B
  __shared__ float Ws[64*RP];       // 81920 B, linear
  __shared__ short Pt[4][16*64];    //  8192 B, linear, per-wave
  int t = threadIdx.x, w = t>>6, l = t&63;
  int qt = blockIdx.x, h = blockIdx.y, b = blockIdx.z;
  const short* Qg  = Q  + ((((b*H_ + h)<<10) + qt*64)*D_);
  const short* Kg  = K  + (((b*H_ + h)<<10)*D_);
  const short* VTg = VT + (((b*H_ + h)*D_)<<10);

  // zero own wave's Ws rows (16 rows x RP floats = 5120)
#pragma unroll
  for (int i=0;i<80;++i) Ws[(w*16)*RP + i*64 + l] = 0.f;

  // Q fragments (A): row = l&15 within wave tile, 8 contiguous d
  bf16x8 aq[2];
#pragma unroll
  for (int kf=0;kf<2;++kf)
    aq[kf] = *(const bf16x8*)(Qg + (w*16 + (l&15))*D_ + (l>>4)*8 + kf*32);

  // QR = Q @ rkB^T (Q pre-scaled by 1/8): cols 0..303
  for (int nt=0; nt<19; ++nt){
    f32x4 c = {0.f,0.f,0.f,0.f};
    int r = nt*16 + (l&15);
#pragma unroll
    for (int kf=0;kf<2;++kf)
      c = MFMA16(aq[kf], *(const bf16x8*)(rkB + r*D_ + (l>>4)*8 + kf*32), c);
#pragma unroll
    for (int j=0;j<4;++j)
      QRs[(w*16 + (l>>4)*4 + j)*QRP + r] = f2bf(c[j]);
  }

  f32x4 av[4]; { f32x4 z = {0.f,0.f,0.f,0.f}; av[0]=z; av[1]=z; av[2]=z; av[3]=z; }
  float Ls[4] = {0.f,0.f,0.f,0.f};

  for (int kt=0; kt<16; ++kt){
    // S = Q K^T, K fragments direct from global
    f32x4 s[4]; { f32x4 z = {0.f,0.f,0.f,0.f}; s[0]=z; s[1]=z; s[2]=z; s[3]=z; }
#pragma unroll
    for (int nt=0;nt<4;++nt)
#pragma unroll
      for (int kf=0;kf<2;++kf){
        bf16x8 kb = *(const bf16x8*)(Kg + (kt*64 + nt*16 + (l&15))*D_ + (l>>4)*8 + kf*32);
        s[nt] = MFMA16(aq[kf], kb, s[nt]);
      }

    // + rel gather, exp, row-sum partials, scatter to Ws, write P
    float pj[4] = {0.f,0.f,0.f,0.f};
#pragma unroll
    for (int nt=0;nt<4;++nt){
      int kg = kt*64 + nt*16 + (l&15);
#pragma unroll
      for (int j=0;j<4;++j){
        int qr = w*16 + (l>>4)*4 + j;                 // local q row 0..63
        int qg = qt*64 + qr;
        int dd = kg - qg; dd = dd < -150 ? -150 : (dd > 150 ? 150 : dd);
        int r  = dd + 150;
        float sv = s[nt][j] + bf2f(QRs[qr*QRP + r]);
        float p  = __expf(sv);
        pj[j] += p;
        atomicAdd(&Ws[qr*RP + r], p);
        Pt[w][((l>>4)*4 + j)*64 + nt*16 + (l&15)] = f2bf(p);
      }
    }
#pragma unroll
    for (int j=0;j<4;++j){
      float v = pj[j];
      v += __shfl_xor(v, 1); v += __shfl_xor(v, 2);
      v += __shfl_xor(v, 4); v += __shfl_xor(v, 8);
      Ls[j] += v;                                     // row-sum over this k-tile
    }
    // weight1 += P @ V, V fragments direct from VT [B,H,D,L]
#pragma unroll
    for (int kf=0;kf<2;++kf){
      bf16x8 pa = *(const bf16x8*)(&Pt[w][(l&15)*64 + (l>>4)*8 + kf*32]);
#pragma unroll
      for (int nt=0;nt<4;++nt){
        bf16x8 vb = *(const bf16x8*)(VTg + ((nt*16 + (l&15))<<10) + kt*64 + (l>>4)*8 + kf*32);
        av[nt] = MFMA16(pa, vb, av[nt]);
      }
    }
  }

  // weight2 += Ws @ rel_v  (K = RP = 320, cols >= 301 are zero)
  for (int kf=0; kf<10; ++kf){
    int row = w*16 + (l&15);
    int c0  = (l>>4)*8 + kf*32;
    float4 f0 = *(const float4*)(&Ws[row*RP + c0]);
    float4 f1 = *(const float4*)(&Ws[row*RP + c0 + 4]);
    bf16x8 wa;
    wa[0]=f2bf(f0.x); wa[1]=f2bf(f0.y); wa[2]=f2bf(f0.z); wa[3]=f2bf(f0.w);
    wa[4]=f2bf(f1.x); wa[5]=f2bf(f1.y); wa[6]=f2bf(f1.z); wa[7]=f2bf(f1.w);
#pragma unroll
    for (int nt=0;nt<4;++nt)
      av[nt] = MFMA16(wa, *(const bf16x8*)(rvT + (nt*16 + (l&15))*RP + c0), av[nt]);
  }

  // normalize by softmax denom and store x[b, q, h*64+d]
  float rl[4];
#pragma unroll
  for (int j=0;j<4;++j) rl[j] = 1.0f / Ls[j];
#pragma unroll
  for (int nt=0;nt<4;++nt){
    int col = h*64 + nt*16 + (l&15);
#pragma unroll
    for (int j=0;j<4;++j){
      int row = (b<<10) + qt*64 + w*16 + (l>>4)*4 + j;
      X[row*HD_ + col] = f2bf(av[nt][j] * rl[j]);
    }
  }
}

// ---------------- Kernel 3: out = X @ Wo (FLOAT32 out) --------------------
__global__ __launch_bounds__(64)
void out_kernel(const short* __restrict__ X, const short* __restrict__ WoT,
                float* __restrict__ out){
  int l = threadIdx.x, mt = blockIdx.x;
  f32x4 acc[4]; { f32x4 z = {0.f,0.f,0.f,0.f}; acc[0]=z; acc[1]=z; acc[2]=z; acc[3]=z; }
  const short* Xg = X + mt*16*HD_;
#pragma unroll
  for (int kf=0; kf<16; ++kf){
    bf16x8 a = *(const bf16x8*)(Xg + (l&15)*HD_ + (l>>4)*8 + kf*32);
#pragma unroll
    for (int nt=0;nt<4;++nt){
      bf16x8 bfr = *(const bf16x8*)(WoT + (nt*16 + (l&15))*HD_ + (l>>4)*8 + kf*32);
      acc[nt] = MFMA16(a, bfr, acc[nt]);
    }
  }
#pragma unroll
  for (int nt=0;nt<4;++nt)
#pragma unroll
    for (int j=0;j<4;++j)
      out[(mt*16 + (l>>4)*4 + j)*D_ + nt*16 + (l&15)] = acc[nt][j];
}

__global__ __launch_bounds__(256)
void zero_out_kernel(float* __restrict__ out, int n){
  int i = blockIdx.x*256 + threadIdx.x;
  if (i < n) out[i] = 0.f;
}

// ---------------- Launch ----------------------------------------------------
extern "C" void kernel_launch(void* const* d_in, const int* in_sizes, int n_in,
                              void* d_out, int out_size, void* d_ws, size_t ws_size,
                              hipStream_t stream){
  (void)in_sizes; (void)n_in;
  const float* q  = (const float*)d_in[0];
  const float* k  = (const float*)d_in[1];
  const float* v  = (const float*)d_in[2];
  const float* Wq = (const float*)d_in[3];
  const float* Wk = (const float*)d_in[4];
  const float* Wv = (const float*)d_in[5];
  const float* Wo = (const float*)d_in[6];
  const float* rk = (const float*)d_in[7];
  const float* rv = (const float*)d_in[8];

  // ws layout (bytes): WqT 0, WkT 64K, WvT 128K, WoT 192K, rvT 262144(40960),
  // rkB 303104(38912), then Q 342016, K, VT, X (8MB each).
  const size_t NEED = 342016u + 4u*8388608u;   // 33,896,448
  if (ws_size < NEED){
    zero_out_kernel<<<(out_size + 255)/256, 256, 0, stream>>>((float*)d_out, out_size);
    return;
  }
  char* ws = (char*)d_ws;
  short* WqT = (short*)(ws);
  short* WkT = (short*)(ws + 65536);
  short* WvT = (short*)(ws + 131072);
  short* WoT = (short*)(ws + 196608);
  short* rvT = (short*)(ws + 262144);
  short* rkB = (short*)(ws + 303104);
  short* Q   = (short*)(ws + 342016);
  short* K   = (short*)(ws + 342016 + 8388608);
  short* VT  = (short*)(ws + 342016 + 2u*8388608);
  short* X   = (short*)(ws + 342016 + 3u*8388608);

  prep_kernel<<<(PREP_TOTAL + 255)/256, 256, 0, stream>>>(Wq, Wk, Wv, Wo, rk, rv, (short*)ws);
  proj_kernel<<<dim3(128, 8, 3), 256, 0, stream>>>(q, k, v, WqT, WkT, WvT, Q, K, VT);
  attn_kernel<<<dim3(16, 8, 8), 256, 0, stream>>>(Q, K, VT, rkB, rvT, X);
  out_kernel<<<512, 64, 0, stream>>>(X, WoT, (float*)d_out);
}

// Round 6
// 214.043 us; speedup vs baseline: 2.5905x; 2.5905x over previous
//
#include <hip/hip_runtime.h>
#include <stdint.h>

// Inputs: float32. Output: float32 (reference's output dtype).
#define B_   8
#define L_   1024
#define D_   64
#define H_   8
#define HD_  512
#define NREL 301
#define RP   320   // rvT row stride
#define RKB  304   // rkB rows (301 + 3 dup of row 300)

// attn LDS strides (shorts)
#define QRSTR 312  // QRs row stride (cols 0..303 used); 312 spreads banks
#define PBSTR 328  // Pband row stride (cols 0..319 used in MFMA); 16B-aligned frags
#define PTSTR 72   // Pt row stride; 16B-aligned b128 frags, balanced banks

typedef short bf16x8 __attribute__((ext_vector_type(8)));
typedef float f32x4  __attribute__((ext_vector_type(4)));

#define MFMA16(a,b,c) __builtin_amdgcn_mfma_f32_16x16x32_bf16((a),(b),(c),0,0,0)

__device__ __forceinline__ float bf2f(short s){
  union { unsigned u; float f; } v; v.u = ((unsigned)(unsigned short)s) << 16; return v.f;
}
__device__ __forceinline__ short f2bf(float f){
  union { float f; unsigned u; } v; v.f = f;
  v.u += ((v.u >> 16) & 1u) + 0x7fffu;   // RNE
  return (short)(v.u >> 16);
}
__device__ __forceinline__ bf16x8 cvt8(const float* p){
  float4 x0 = *(const float4*)p, x1 = *(const float4*)(p + 4);
  bf16x8 r;
  r[0]=f2bf(x0.x); r[1]=f2bf(x0.y); r[2]=f2bf(x0.z); r[3]=f2bf(x0.w);
  r[4]=f2bf(x1.x); r[5]=f2bf(x1.y); r[6]=f2bf(x1.z); r[7]=f2bf(x1.w);
  return r;
}

// ---------------- Kernel 0: weight transpose + f32->bf16 into workspace -----
#define PREP_TOTAL (4*32768 + 64*RP + RKB*64)   // 171008
__global__ __launch_bounds__(256)
void prep_kernel(const float* __restrict__ Wq, const float* __restrict__ Wk,
                 const float* __restrict__ Wv, const float* __restrict__ Wo,
                 const float* __restrict__ rk, const float* __restrict__ rv,
                 short* __restrict__ ws16){
  int idx = blockIdx.x*256 + threadIdx.x;
  short* WqT = ws16;                 // [512][64]
  short* WkT = ws16 + 32768;
  short* WvT = ws16 + 65536;
  short* WoT = ws16 + 98304;         // [64][512]
  short* rvT = ws16 + 131072;        // [64][RP], cols>=301 zero
  short* rkB = ws16 + 131072 + 64*RP;// [RKB][64], rows>=301 dup row 300
  if (idx < 32768){ WqT[idx] = f2bf(Wq[(idx&63)*HD_ + (idx>>6)]); return; }
  idx -= 32768;
  if (idx < 32768){ WkT[idx] = f2bf(Wk[(idx&63)*HD_ + (idx>>6)]); return; }
  idx -= 32768;
  if (idx < 32768){ WvT[idx] = f2bf(Wv[(idx&63)*HD_ + (idx>>6)]); return; }
  idx -= 32768;
  if (idx < 32768){ WoT[idx] = f2bf(Wo[(idx&511)*D_ + (idx>>9)]); return; }
  idx -= 32768;
  if (idx < 64*RP){ int c = idx/RP, r = idx - c*RP;
                    rvT[idx] = (r < NREL) ? f2bf(rv[r*D_ + c]) : (short)0; return; }
  idx -= 64*RP;
  if (idx < RKB*64){ int tr = idx>>6, d = idx&63;
                     int src = (tr > 300) ? 300 : tr;
                     rkB[idx] = f2bf(rk[src*D_ + d]); }
}

// ---------------- Kernel 1: fused QKV projection — direct loads, no LDS ----
__global__ __launch_bounds__(256)
void proj_kernel(const float* __restrict__ qin, const float* __restrict__ kin,
                 const float* __restrict__ vin,
                 const short* __restrict__ WqT, const short* __restrict__ WkT,
                 const short* __restrict__ WvT,
                 short* __restrict__ Qo, short* __restrict__ Ko, short* __restrict__ VTo){
  int t = threadIdx.x, w = t>>6, l = t&63;
  int mt = blockIdx.x, ny = blockIdx.y, mat = blockIdx.z;
  const float* in = (mat==0) ? qin : (mat==1 ? kin : vin);
  const short* WT = (mat==0) ? WqT : (mat==1 ? WkT : WvT);
  int arow = mt*64 + w*16 + (l&15);
  bf16x8 a[2];
#pragma unroll
  for (int kf=0;kf<2;++kf)
    a[kf] = cvt8(in + arow*D_ + (l>>4)*8 + kf*32);
  f32x4 acc[4];
#pragma unroll
  for (int nt=0;nt<4;++nt){
    f32x4 z = {0.f,0.f,0.f,0.f}; acc[nt] = z;
#pragma unroll
    for (int kf=0;kf<2;++kf){
      bf16x8 bfr = *(const bf16x8*)(WT + (ny*64 + nt*16 + (l&15))*D_ + (l>>4)*8 + kf*32);
      acc[nt] = MFMA16(a[kf], bfr, acc[nt]);
    }
  }
  float scale = (mat==0) ? 0.125f : 1.0f;   // fold 1/sqrt(64) into Q
#pragma unroll
  for (int nt=0;nt<4;++nt){
    int hd = ny*64 + nt*16 + (l&15);
    int h = hd >> 6, d = hd & 63;
#pragma unroll
    for (int j=0;j<4;++j){
      int m = mt*64 + w*16 + (l>>4)*4 + j;
      int b = m >> 10, lr = m & 1023;
      short vv = f2bf(acc[nt][j] * scale);
      if (mat==2) VTo[(((b*H_ + h)*D_ + d)<<10) + lr] = vv;          // [B,H,D,L]
      else {
        short* O = (mat==0) ? Qo : Ko;                               // [B,H,L,D]
        O[((((b*H_ + h)<<10) + lr)*D_) + d] = vv;
      }
    }
  }
}

// ---------------- Kernel 2: fused relative attention -----------------------
// One wave per block, 16 q rows. No atomics: interior of the rel-scatter is a
// bijection (w2[q,r] = P[q, q+r-150] for 0<r<300); edges r=0/300 are register
// sums E0/E1. LDS ~22.3KB -> 7 blocks/CU.
__global__ __launch_bounds__(64)
void attn_kernel(const short* __restrict__ Q, const short* __restrict__ K,
                 const short* __restrict__ VT, const short* __restrict__ rkB,
                 const short* __restrict__ rvT, short* __restrict__ X){
  __shared__ short QRs[16*QRSTR];    // 9984 B: q·rel_k table (bf16)
  __shared__ short Pband[16*PBSTR];  // 10496 B: banded P + edge sums
  __shared__ short Pt[16*PTSTR];     // 2304 B: P tile transpose for PV
  int l = threadIdx.x, g = l>>4, c = l&15;
  int qt = blockIdx.x, h = blockIdx.y, b = blockIdx.z;
  int q0 = qt*16;
  const short* Qg  = Q  + ((((b*H_ + h)<<10) + q0)*D_);
  const short* Kg  = K  + (((b*H_ + h)<<10)*D_);
  const short* VTg = VT + (((b*H_ + h)*D_)<<10);

  // zero Pband (16*PBSTR shorts = 656 uint4)
  { uint4 z = {0,0,0,0};
#pragma unroll
    for (int i=0;i<11;++i){ int u = i*64 + l; if (u < 16*PBSTR/8) ((uint4*)Pband)[u] = z; } }

  // Q A-frags: row q_local = c, k = g*8 + kf*32 .. +8   (Q pre-scaled by 1/8)
  bf16x8 aq[2];
#pragma unroll
  for (int kf=0;kf<2;++kf)
    aq[kf] = *(const bf16x8*)(Qg + c*D_ + g*8 + kf*32);

  // QR table: QR[q][r] = q · rkB[r],  r = nt*16+c in [0,303]
  for (int nt=0; nt<19; ++nt){
    f32x4 cf = {0.f,0.f,0.f,0.f};
    int r = nt*16 + c;
#pragma unroll
    for (int kf=0;kf<2;++kf)
      cf = MFMA16(aq[kf], *(const bf16x8*)(rkB + r*D_ + g*8 + kf*32), cf);
#pragma unroll
    for (int j=0;j<4;++j)
      QRs[(4*g + j)*QRSTR + r] = f2bf(cf[j]);
  }

  f32x4 av[4]; { f32x4 z = {0.f,0.f,0.f,0.f}; av[0]=z; av[1]=z; av[2]=z; av[3]=z; }
  float pj[4] = {0.f,0.f,0.f,0.f}, e0[4] = {0.f,0.f,0.f,0.f}, e1[4] = {0.f,0.f,0.f,0.f};

  // preload K frags for tile 0
  bf16x8 kb[4][2], kn[4][2], vb[4][2];
#pragma unroll
  for (int nt=0;nt<4;++nt)
#pragma unroll
    for (int kf=0;kf<2;++kf)
      kb[nt][kf] = *(const bf16x8*)(Kg + (nt*16 + c)*D_ + g*8 + kf*32);

  for (int kt=0; kt<16; ++kt){
    // issue V loads for this tile and K loads for next tile early
#pragma unroll
    for (int nt=0;nt<4;++nt)
#pragma unroll
      for (int kf=0;kf<2;++kf)
        vb[nt][kf] = *(const bf16x8*)(VTg + ((nt*16 + c)<<10) + kt*64 + g*8 + kf*32);
    int ktn = (kt < 15) ? kt+1 : 15;
#pragma unroll
    for (int nt=0;nt<4;++nt)
#pragma unroll
      for (int kf=0;kf<2;++kf)
        kn[nt][kf] = *(const bf16x8*)(Kg + (ktn*64 + nt*16 + c)*D_ + g*8 + kf*32);

    // S = Q K^T (scaled): s[nt][j] = S[q=4g+j][k = nt*16+c]
    f32x4 s[4]; { f32x4 z = {0.f,0.f,0.f,0.f}; s[0]=z; s[1]=z; s[2]=z; s[3]=z; }
#pragma unroll
    for (int nt=0;nt<4;++nt)
#pragma unroll
      for (int kf=0;kf<2;++kf)
        s[nt] = MFMA16(aq[kf], kb[nt][kf], s[nt]);

    // softmax: rel gather + exp; band write (unique) or edge accumulate
#pragma unroll
    for (int nt=0;nt<4;++nt){
      int kg = kt*64 + nt*16 + c;
#pragma unroll
      for (int j=0;j<4;++j){
        int ql = 4*g + j;
        int dd = kg - (q0 + ql);
        int r  = (dd < -150 ? -150 : (dd > 150 ? 150 : dd)) + 150;
        float sv = s[nt][j] + bf2f(QRs[ql*QRSTR + r]);
        float p  = __expf(sv);
        pj[j] += p;
        short pb = f2bf(p);
        if (dd <= -150)      e0[j] += p;
        else if (dd >= 150)  e1[j] += p;
        else                 Pband[ql*PBSTR + dd + 150] = pb;
        Pt[ql*PTSTR + nt*16 + c] = pb;
      }
    }

    // weight1 += P @ V
#pragma unroll
    for (int kf=0;kf<2;++kf){
      bf16x8 pa = *(const bf16x8*)(Pt + c*PTSTR + g*8 + kf*32);
#pragma unroll
      for (int nt=0;nt<4;++nt)
        av[nt] = MFMA16(pa, vb[nt][kf], av[nt]);
    }
#pragma unroll
    for (int nt=0;nt<4;++nt)
#pragma unroll
      for (int kf=0;kf<2;++kf)
        kb[nt][kf] = kn[nt][kf];
  }

  // reduce row-sums and edges over the 16 lanes of each group
#pragma unroll
  for (int j=0;j<4;++j){
    float v = pj[j];
    v += __shfl_xor(v,1); v += __shfl_xor(v,2); v += __shfl_xor(v,4); v += __shfl_xor(v,8);
    pj[j] = v;
    float a0 = e0[j];
    a0 += __shfl_xor(a0,1); a0 += __shfl_xor(a0,2); a0 += __shfl_xor(a0,4); a0 += __shfl_xor(a0,8);
    e0[j] = a0;
    float a1 = e1[j];
    a1 += __shfl_xor(a1,1); a1 += __shfl_xor(a1,2); a1 += __shfl_xor(a1,4); a1 += __shfl_xor(a1,8);
    e1[j] = a1;
  }
  if (c == 0){
#pragma unroll
    for (int j=0;j<4;++j){
      Pband[(4*g + j)*PBSTR + 0]   = f2bf(e0[j]);
      Pband[(4*g + j)*PBSTR + 300] = f2bf(e1[j]);
    }
  }

  // weight2 += Pband @ rel_v   (K = 320, cols 301..319 zero both sides)
#pragma unroll
  for (int kf=0; kf<10; ++kf){
    bf16x8 wa = *(const bf16x8*)(Pband + c*PBSTR + g*8 + kf*32);
#pragma unroll
    for (int nt=0;nt<4;++nt)
      av[nt] = MFMA16(wa, *(const bf16x8*)(rvT + (nt*16 + c)*RP + g*8 + kf*32), av[nt]);
  }

  // normalize by softmax denom and store x[b, q, h*64+d]
  float rl[4];
#pragma unroll
  for (int j=0;j<4;++j) rl[j] = 1.0f / pj[j];
#pragma unroll
  for (int nt=0;nt<4;++nt){
    int col = h*64 + nt*16 + c;
#pragma unroll
    for (int j=0;j<4;++j){
      int row = (b<<10) + q0 + 4*g + j;
      X[row*HD_ + col] = f2bf(av[nt][j] * rl[j]);
    }
  }
}

// ---------------- Kernel 3: out = X @ Wo (FLOAT32 out) --------------------
__global__ __launch_bounds__(64)
void out_kernel(const short* __restrict__ X, const short* __restrict__ WoT,
                float* __restrict__ out){
  int l = threadIdx.x, mt = blockIdx.x;
  f32x4 acc[4]; { f32x4 z = {0.f,0.f,0.f,0.f}; acc[0]=z; acc[1]=z; acc[2]=z; acc[3]=z; }
  const short* Xg = X + mt*16*HD_;
#pragma unroll
  for (int kf=0; kf<16; ++kf){
    bf16x8 a = *(const bf16x8*)(Xg + (l&15)*HD_ + (l>>4)*8 + kf*32);
#pragma unroll
    for (int nt=0;nt<4;++nt){
      bf16x8 bfr = *(const bf16x8*)(WoT + (nt*16 + (l&15))*HD_ + (l>>4)*8 + kf*32);
      acc[nt] = MFMA16(a, bfr, acc[nt]);
    }
  }
#pragma unroll
  for (int nt=0;nt<4;++nt)
#pragma unroll
    for (int j=0;j<4;++j)
      out[(mt*16 + (l>>4)*4 + j)*D_ + nt*16 + (l&15)] = acc[nt][j];
}

__global__ __launch_bounds__(256)
void zero_out_kernel(float* __restrict__ out, int n){
  int i = blockIdx.x*256 + threadIdx.x;
  if (i < n) out[i] = 0.f;
}

// ---------------- Launch ----------------------------------------------------
extern "C" void kernel_launch(void* const* d_in, const int* in_sizes, int n_in,
                              void* d_out, int out_size, void* d_ws, size_t ws_size,
                              hipStream_t stream){
  (void)in_sizes; (void)n_in;
  const float* q  = (const float*)d_in[0];
  const float* k  = (const float*)d_in[1];
  const float* v  = (const float*)d_in[2];
  const float* Wq = (const float*)d_in[3];
  const float* Wk = (const float*)d_in[4];
  const float* Wv = (const float*)d_in[5];
  const float* Wo = (const float*)d_in[6];
  const float* rk = (const float*)d_in[7];
  const float* rv = (const float*)d_in[8];

  // ws layout (bytes): WqT 0, WkT 64K, WvT 128K, WoT 192K, rvT 262144(40960),
  // rkB 303104(38912), then Q 342016, K, VT, X (8MB each).
  const size_t NEED = 342016u + 4u*8388608u;   // 33,896,448
  if (ws_size < NEED){
    zero_out_kernel<<<(out_size + 255)/256, 256, 0, stream>>>((float*)d_out, out_size);
    return;
  }
  char* ws = (char*)d_ws;
  short* WqT = (short*)(ws);
  short* WkT = (short*)(ws + 65536);
  short* WvT = (short*)(ws + 131072);
  short* WoT = (short*)(ws + 196608);
  short* rvT = (short*)(ws + 262144);
  short* rkB = (short*)(ws + 303104);
  short* Q   = (short*)(ws + 342016);
  short* K   = (short*)(ws + 342016 + 8388608);
  short* VT  = (short*)(ws + 342016 + 2u*8388608);
  short* X   = (short*)(ws + 342016 + 3u*8388608);

  prep_kernel<<<(PREP_TOTAL + 255)/256, 256, 0, stream>>>(Wq, Wk, Wv, Wo, rk, rv, (short*)ws);
  proj_kernel<<<dim3(128, 8, 3), 256, 0, stream>>>(q, k, v, WqT, WkT, WvT, Q, K, VT);
  attn_kernel<<<dim3(64, 8, 8), 64, 0, stream>>>(Q, K, VT, rkB, rvT, X);
  out_kernel<<<512, 64, 0, stream>>>(X, WoT, (float*)d_out);
}